// Round 1
// baseline (1014.126 us; speedup 1.0000x reference)
//
#include <hip/hip_runtime.h>
#include <math.h>

#define B_   2
#define H_   64
#define W_   64
#define DM   96
#define DE   192
#define NST  16
#define RNK  6
#define KD   4
#define L_   (H_*W_)          // 4096
#define CDBL (RNK + 2*NST)    // 38
#define NCHUNK 32
#define LC   (L_/NCHUNK)      // 128

// ---- workspace layout (floats) ----
#define OFF_XP    0
#define SZ_XP     (B_*L_*DE)                 // 1,572,864
#define OFF_ZS    (OFF_XP + SZ_XP)
#define SZ_ZS     (B_*L_*DE)
#define OFF_XC    (OFF_ZS + SZ_ZS)
#define SZ_XC     (B_*L_*DE)
#define OFF_XDBL  (OFF_XC + SZ_XC)
#define SZ_XDBL   (B_*KD*L_*CDBL)            // 1,245,184
#define OFF_DELTA (OFF_XDBL + SZ_XDBL)
#define SZ_DELTA  (B_*KD*L_*DE)              // 6,291,456
#define OFF_APROD (OFF_DELTA + SZ_DELTA)
#define SZ_SUMM   (B_*KD*DE*NST*NCHUNK)      // 786,432
#define OFF_HLOC  (OFF_APROD + SZ_SUMM)
#define OFF_YS    (OFF_HLOC + SZ_SUMM)
#define SZ_YS     (B_*KD*L_*DE)

__device__ __forceinline__ int map_dir(int k, int l) {
    // index into xc's (h*W+w) flattening for scan position l of direction k
    int lp = (k & 1) ? (L_ - 1 - l) : l;
    if (k >= 2) lp = ((lp & 63) << 6) | (lp >> 6);   // (l%H)*W + l/H
    return lp;
}

__device__ __forceinline__ float silu(float x) { return x / (1.f + __expf(-x)); }

// K1: xz = x @ in_proj_w.T ; split -> xp (b,l,de), zs = silu(z) (b,l,de)
__global__ void k_inproj(const float* __restrict__ x, const float* __restrict__ Wp,
                         float* __restrict__ xp, float* __restrict__ zs) {
    __shared__ float sx[8][DM];
    int r0 = blockIdx.x * 8;
    int t = threadIdx.x;                    // 0..383 = output index o
    for (int i = t; i < 8 * DM; i += 384) {
        sx[i / DM][i % DM] = x[(r0 + i / DM) * DM + (i % DM)];
    }
    __syncthreads();
    float acc[8] = {0, 0, 0, 0, 0, 0, 0, 0};
    const float4* wrow = (const float4*)(Wp + t * DM);
#pragma unroll
    for (int i4 = 0; i4 < DM / 4; ++i4) {
        float4 w4 = wrow[i4];
#pragma unroll
        for (int j = 0; j < 8; ++j) {
            float4 x4 = ((const float4*)sx[j])[i4];
            acc[j] += w4.x * x4.x + w4.y * x4.y + w4.z * x4.z + w4.w * x4.w;
        }
    }
#pragma unroll
    for (int j = 0; j < 8; ++j) {
        int r = r0 + j;
        if (t < DE) xp[r * DE + t] = acc[j];
        else        zs[r * DE + (t - DE)] = silu(acc[j]);
    }
}

// K2: depthwise 3x3 conv (pad 1) + bias + silu, NHWC
__global__ void k_conv(const float* __restrict__ xp, const float* __restrict__ cw,
                       const float* __restrict__ cb, float* __restrict__ xc) {
    int d = threadIdx.x;                     // 0..191
    int r = blockIdx.x;                      // b*L + l
    int b = r >> 12, l = r & (L_ - 1);
    int h = l >> 6, w = l & 63;
    float acc = cb[d];
#pragma unroll
    for (int dy = -1; dy <= 1; ++dy)
#pragma unroll
        for (int dx = -1; dx <= 1; ++dx) {
            int hh = h + dy, ww = w + dx;
            if (hh >= 0 && hh < H_ && ww >= 0 && ww < W_)
                acc += xp[((b * L_ + hh * W_ + ww) * DE) + d] * cw[d * 9 + (dy + 1) * 3 + (dx + 1)];
        }
    xc[r * DE + d] = silu(acc);
}

// K3: x_dbl[b,k,l,c] = sum_d xs[b,k,d,l] * x_proj_weight[k,c,d]
__global__ void k_xdbl(const float* __restrict__ xc, const float* __restrict__ xpw,
                       float* __restrict__ xdbl) {
    int t = blockIdx.x * 256 + threadIdx.x;  // B*K*L*38 = 1,245,184 exact
    int c = t % CDBL; int u = t / CDBL;
    int l = u % L_;  int v = u / L_;
    int k = v % KD;  int b = v / KD;
    int m = map_dir(k, l);
    const float4* xr = (const float4*)(xc + (b * L_ + m) * DE);
    const float4* wr = (const float4*)(xpw + (k * CDBL + c) * DE);
    float acc = 0.f;
#pragma unroll 8
    for (int i = 0; i < DE / 4; ++i) {
        float4 a = xr[i], w4 = wr[i];
        acc += a.x * w4.x + a.y * w4.y + a.z * w4.z + a.w * w4.w;
    }
    xdbl[t] = acc;
}

// K4: delta[b,k,l,d] = softplus( sum_r x_dbl[b,k,l,r]*dtw[k,d,r] + dtb[k,d] )
__global__ void k_delta(const float* __restrict__ xdbl, const float* __restrict__ dtw,
                        const float* __restrict__ dtb, float* __restrict__ delta) {
    int t = blockIdx.x * 256 + threadIdx.x;  // B*K*L*DE = 6,291,456 exact
    int d = t % DE; int u = t / DE;
    int l = u % L_; int v = u / L_;
    int k = v % KD; int b = v / KD;
    const float* xr = xdbl + ((b * KD + k) * L_ + l) * CDBL;
    const float* wr = dtw + (k * DE + d) * RNK;
    float acc = dtb[k * DE + d];
#pragma unroll
    for (int r = 0; r < RNK; ++r) acc += xr[r] * wr[r];
    delta[t] = (acc > 20.f) ? acc : log1pf(__expf(acc));
}

// K5 (phase A): per-chunk local scan: h_local and decay product (no y)
__global__ void k_scanA(const float* __restrict__ delta, const float* __restrict__ xc,
                        const float* __restrict__ xdbl, const float* __restrict__ Alog,
                        float* __restrict__ aprod, float* __restrict__ hloc) {
    int wid = (blockIdx.x * 256 + threadIdx.x) >> 6;   // 12288 waves
    int lane = threadIdx.x & 63;
    int chunk = wid & (NCHUNK - 1);
    int g = wid >> 5;                 // (b,k,dgrp)
    int dgrp = g % 48; int v = g / 48;
    int k = v & 3, b = v >> 2;
    int dg = lane & 3, n = lane >> 2;
    int d = dgrp * 4 + dg;
    float Aval = -__expf(Alog[(k * DE + d) * NST + n]);
    const float* dptr = delta + ((b * KD + k) * L_) * DE + d;
    const float* xptr = xc + (b * L_) * DE + d;
    const float* bptr = xdbl + ((b * KD + k) * L_) * CDBL + RNK + n;
    float h = 0.f, ap = 1.f;
    int l0 = chunk * LC;
#pragma unroll 4
    for (int ll = 0; ll < LC; ++ll) {
        int l = l0 + ll;
        float dt = dptr[l * DE];
        float uu = xptr[map_dir(k, l) * DE];
        float bv = bptr[l * CDBL];
        float a = __expf(dt * Aval);
        h = fmaf(a, h, dt * uu * bv);
        ap *= a;
    }
    aprod[wid * 64 + lane] = ap;
    hloc[wid * 64 + lane] = h;
}

// K6 (phase B): sequential scan across chunk summaries; hloc[c] <- carry-in state
__global__ void k_scanB(const float* __restrict__ aprod, float* __restrict__ hloc) {
    int t = blockIdx.x * 256 + threadIdx.x;  // 24576 chains
    int lane = t & 63; int g = t >> 6;
    float carry = 0.f;
#pragma unroll
    for (int c = 0; c < NCHUNK; ++c) {
        int idx = (g * NCHUNK + c) * 64 + lane;
        float a = aprod[idx];
        float hl = hloc[idx];
        hloc[idx] = carry;
        carry = fmaf(a, carry, hl);
    }
}

// K7 (phase C): re-run chunks with carry-in, compute y via 16-lane butterfly
__global__ void k_scanC(const float* __restrict__ delta, const float* __restrict__ xc,
                        const float* __restrict__ xdbl, const float* __restrict__ Alog,
                        const float* __restrict__ hin, float* __restrict__ ys) {
    int wid = (blockIdx.x * 256 + threadIdx.x) >> 6;
    int lane = threadIdx.x & 63;
    int chunk = wid & (NCHUNK - 1);
    int g = wid >> 5;
    int dgrp = g % 48; int v = g / 48;
    int k = v & 3, b = v >> 2;
    int dg = lane & 3, n = lane >> 2;
    int d = dgrp * 4 + dg;
    float Aval = -__expf(Alog[(k * DE + d) * NST + n]);
    const float* dptr = delta + ((b * KD + k) * L_) * DE + d;
    const float* xptr = xc + (b * L_) * DE + d;
    const float* bptr = xdbl + ((b * KD + k) * L_) * CDBL + RNK + n;
    const float* cptr = bptr + NST;
    float* yptr = ys + ((b * KD + k) * L_) * DE + d;
    float h = hin[wid * 64 + lane];
    int l0 = chunk * LC;
#pragma unroll 2
    for (int ll = 0; ll < LC; ++ll) {
        int l = l0 + ll;
        float dt = dptr[l * DE];
        float uu = xptr[map_dir(k, l) * DE];
        float bv = bptr[l * CDBL];
        float cv = cptr[l * CDBL];
        float a = __expf(dt * Aval);
        h = fmaf(a, h, dt * uu * bv);
        float p = h * cv;
        p += __shfl_xor(p, 4);
        p += __shfl_xor(p, 8);
        p += __shfl_xor(p, 16);
        p += __shfl_xor(p, 32);
        if (n == 0) yptr[l * DE] = p;   // 4 consecutive floats per wave-step
    }
}

// K8: combine 4 directions + u*sum(Ds) + LayerNorm + silu(z) gate + out-proj
__global__ void k_final(const float* __restrict__ ys, const float* __restrict__ xc,
                        const float* __restrict__ Ds, const float* __restrict__ lnw,
                        const float* __restrict__ lnb, const float* __restrict__ zs,
                        const float* __restrict__ Wout, float* __restrict__ out) {
    int r = blockIdx.x;                      // b*L + l
    int d = threadIdx.x;                     // 0..191
    int b = r >> 12, l = r & (L_ - 1);
    int lv = ((l & 63) << 6) | (l >> 6);
    const float* ysb = ys + (size_t)(b * KD) * L_ * DE;
    float s = ysb[(0 * L_ + l) * DE + d]
            + ysb[(1 * L_ + (L_ - 1 - l)) * DE + d]
            + ysb[(2 * L_ + lv) * DE + d]
            + ysb[(3 * L_ + (L_ - 1 - lv)) * DE + d];
    float sds = Ds[d] + Ds[DE + d] + Ds[2 * DE + d] + Ds[3 * DE + d];
    s += xc[r * DE + d] * sds;

    // LayerNorm over 192 channels
    __shared__ float red[2][4];
    float sum = s, sq = s * s;
#pragma unroll
    for (int off = 32; off >= 1; off >>= 1) {
        sum += __shfl_xor(sum, off);
        sq  += __shfl_xor(sq, off);
    }
    int warp = d >> 6;
    if ((d & 63) == 0) { red[0][warp] = sum; red[1][warp] = sq; }
    __syncthreads();
    float tot  = red[0][0] + red[0][1] + red[0][2];
    float totq = red[1][0] + red[1][1] + red[1][2];
    float mu = tot / DE;
    float var = totq / DE - mu * mu;
    float rstd = rsqrtf(var + 1e-5f);
    float yz = ((s - mu) * rstd * lnw[d] + lnb[d]) * zs[r * DE + d];

    __shared__ float yrow[DE];
    yrow[d] = yz;
    __syncthreads();
    if (d < DM) {
        const float4* wr = (const float4*)(Wout + d * DE);
        const float4* yr = (const float4*)yrow;
        float acc = 0.f;
#pragma unroll 8
        for (int i = 0; i < DE / 4; ++i) {
            float4 w4 = wr[i], y4 = yr[i];
            acc += w4.x * y4.x + w4.y * y4.y + w4.z * y4.z + w4.w * y4.w;
        }
        out[r * DM + d] = acc;
    }
}

extern "C" void kernel_launch(void* const* d_in, const int* in_sizes, int n_in,
                              void* d_out, int out_size, void* d_ws, size_t ws_size,
                              hipStream_t stream) {
    const float* x    = (const float*)d_in[0];
    const float* Wp   = (const float*)d_in[1];
    const float* cw   = (const float*)d_in[2];
    const float* cb   = (const float*)d_in[3];
    const float* xpw  = (const float*)d_in[4];
    const float* dtw  = (const float*)d_in[5];
    const float* dtb  = (const float*)d_in[6];
    const float* Alog = (const float*)d_in[7];
    const float* Ds   = (const float*)d_in[8];
    const float* lnw  = (const float*)d_in[9];
    const float* lnb  = (const float*)d_in[10];
    const float* Wout = (const float*)d_in[11];
    float* out = (float*)d_out;

    float* ws = (float*)d_ws;
    float* xp    = ws + OFF_XP;
    float* zs    = ws + OFF_ZS;
    float* xc    = ws + OFF_XC;
    float* xdbl  = ws + OFF_XDBL;
    float* delta = ws + OFF_DELTA;
    float* aprod = ws + OFF_APROD;
    float* hloc  = ws + OFF_HLOC;
    float* ys    = ws + OFF_YS;

    k_inproj<<<B_ * L_ / 8, 384, 0, stream>>>(x, Wp, xp, zs);
    k_conv<<<B_ * L_, DE, 0, stream>>>(xp, cw, cb, xc);
    k_xdbl<<<(B_ * KD * L_ * CDBL) / 256, 256, 0, stream>>>(xc, xpw, xdbl);
    k_delta<<<(B_ * KD * L_ * DE) / 256, 256, 0, stream>>>(xdbl, dtw, dtb, delta);
    k_scanA<<<(B_ * KD * 48 * NCHUNK) / 4, 256, 0, stream>>>(delta, xc, xdbl, Alog, aprod, hloc);
    k_scanB<<<(B_ * KD * 48 * 64) / 256, 256, 0, stream>>>(aprod, hloc);
    k_scanC<<<(B_ * KD * 48 * NCHUNK) / 4, 256, 0, stream>>>(delta, xc, xdbl, Alog, hloc, ys);
    k_final<<<B_ * L_, DE, 0, stream>>>(ys, xc, Ds, lnw, lnb, zs, Wout, out);
}